// Round 1
// baseline (347.504 us; speedup 1.0000x reference)
//
#include <hip/hip_runtime.h>
#include <cstdint>
#include <cstddef>

#define T_SEQ 2048
#define DIN   4096
#define DOUT  4096
#define RR    64
#define BT_TOTAL 16384   // B*T = 8*2048

// ---------------------------------------------------------------------------
// Kernel 1: inter[m][r] = sum_k x[m][k] * A[adapter(m)][k][r]
// grid.x = BT/32 = 512 blocks, block = 256 threads
// Tile: 32 rows x 64 cols, K-tiles of 64.
// ---------------------------------------------------------------------------
__global__ __launch_bounds__(256) void k_xa(
    const float* __restrict__ x, const int* __restrict__ idx,
    const float* __restrict__ A, float* __restrict__ inter)
{
    __shared__ float xs[64][33];  // [kk][m], +1 pad (writes 2-way, reads broadcast)
    __shared__ float as[64][64];  // [kk][r]

    const int m0 = blockIdx.x * 32;
    const int a  = idx[m0 / T_SEQ];
    const float* __restrict__ Ab = A + (size_t)a * DIN * RR;

    const int t  = threadIdx.x;
    const int tc = t & 15;        // 0..15
    const int tr = t >> 4;        // 0..15
    const int c0 = tc * 4;        // col group (also k-offset for loads)
    const int r0 = tr * 2;        // 2 rows per thread

    float acc[2][4] = {};

    for (int k0 = 0; k0 < DIN; k0 += 64) {
        // ---- load x tile (32 rows x 64 k), store transposed xs[kk][m] ----
        #pragma unroll
        for (int it = 0; it < 2; ++it) {
            int row = tr + it * 16;                       // 0..31
            float4 v = *(const float4*)&x[(size_t)(m0 + row) * DIN + k0 + c0];
            xs[c0 + 0][row] = v.x;
            xs[c0 + 1][row] = v.y;
            xs[c0 + 2][row] = v.z;
            xs[c0 + 3][row] = v.w;
        }
        // ---- load A tile (64 k x 64 r), natural layout ----
        #pragma unroll
        for (int it = 0; it < 4; ++it) {
            int kk = tr + it * 16;                        // 0..63
            *(float4*)&as[kk][c0] =
                *(const float4*)&Ab[(size_t)(k0 + kk) * RR + c0];
        }
        __syncthreads();

        #pragma unroll 8
        for (int kk = 0; kk < 64; ++kk) {
            float4 av = *(const float4*)&as[kk][c0];
            float x0 = xs[kk][r0 + 0];
            float x1 = xs[kk][r0 + 1];
            acc[0][0] += x0 * av.x; acc[0][1] += x0 * av.y;
            acc[0][2] += x0 * av.z; acc[0][3] += x0 * av.w;
            acc[1][0] += x1 * av.x; acc[1][1] += x1 * av.y;
            acc[1][2] += x1 * av.z; acc[1][3] += x1 * av.w;
        }
        __syncthreads();
    }

    #pragma unroll
    for (int i = 0; i < 2; ++i) {
        float4 v = make_float4(acc[i][0], acc[i][1], acc[i][2], acc[i][3]);
        *(float4*)&inter[(size_t)(m0 + r0 + i) * RR + c0] = v;
    }
}

// ---------------------------------------------------------------------------
// Kernel 2: out[m][o] = base[m][o] + s * sum_r inter[m][r] * B[adapter][r][o]
// grid = (DOUT/64, BT/64) = (64, 256), block = 256 threads
// Tile: 64 rows x 64 cols, K = 64 (single tile).
// ---------------------------------------------------------------------------
__global__ __launch_bounds__(256) void k_by(
    const float* __restrict__ inter, const float* __restrict__ base,
    const int* __restrict__ idx, const float* __restrict__ Bw,
    const float* __restrict__ scal, float* __restrict__ out)
{
    __shared__ float its[64][65]; // [kk][m]
    __shared__ float bs [64][64]; // [kk][o]

    const int o0 = blockIdx.x * 64;
    const int m0 = blockIdx.y * 64;
    const int a  = idx[m0 / T_SEQ];
    const float s = scal[a];
    const float* __restrict__ Bb = Bw + (size_t)a * RR * DOUT;

    const int t  = threadIdx.x;
    const int tc = t & 15;
    const int tr = t >> 4;
    const int c0 = tc * 4;
    const int r0 = tr * 4;

    // ---- load inter tile (64 rows x 64 r), store transposed its[kk][m] ----
    #pragma unroll
    for (int it = 0; it < 4; ++it) {
        int row = tr + it * 16;                           // 0..63
        float4 v = *(const float4*)&inter[(size_t)(m0 + row) * RR + c0];
        its[c0 + 0][row] = v.x;
        its[c0 + 1][row] = v.y;
        its[c0 + 2][row] = v.z;
        its[c0 + 3][row] = v.w;
    }
    // ---- load B tile (64 r x 64 o), natural layout ----
    #pragma unroll
    for (int it = 0; it < 4; ++it) {
        int kk = tr + it * 16;
        *(float4*)&bs[kk][c0] =
            *(const float4*)&Bb[(size_t)kk * DOUT + o0 + c0];
    }
    __syncthreads();

    float acc[4][4] = {};
    #pragma unroll 8
    for (int kk = 0; kk < 64; ++kk) {
        float4 bv = *(const float4*)&bs[kk][c0];
        #pragma unroll
        for (int i = 0; i < 4; ++i) {
            float xv = its[kk][r0 + i];
            acc[i][0] += xv * bv.x; acc[i][1] += xv * bv.y;
            acc[i][2] += xv * bv.z; acc[i][3] += xv * bv.w;
        }
    }

    #pragma unroll
    for (int i = 0; i < 4; ++i) {
        size_t off = (size_t)(m0 + r0 + i) * DOUT + o0 + c0;
        float4 bvv = *(const float4*)&base[off];
        float4 o;
        o.x = bvv.x + s * acc[i][0];
        o.y = bvv.y + s * acc[i][1];
        o.z = bvv.z + s * acc[i][2];
        o.w = bvv.w + s * acc[i][3];
        *(float4*)&out[off] = o;
    }
}

// ---------------------------------------------------------------------------
extern "C" void kernel_launch(void* const* d_in, const int* in_sizes, int n_in,
                              void* d_out, int out_size, void* d_ws, size_t ws_size,
                              hipStream_t stream)
{
    const float* x    = (const float*)d_in[0];
    const float* base = (const float*)d_in[1];
    const int*   idx  = (const int*)  d_in[2];
    const float* A    = (const float*)d_in[3];
    const float* Bw   = (const float*)d_in[4];
    const float* scal = (const float*)d_in[5];
    float* out   = (float*)d_out;
    float* inter = (float*)d_ws;     // 16384*64*4 = 4 MB scratch

    k_xa<<<dim3(BT_TOTAL / 32), 256, 0, stream>>>(x, idx, A, inter);
    k_by<<<dim3(DOUT / 64, BT_TOTAL / 64), 256, 0, stream>>>(inter, base, idx, Bw, scal, out);
}